// Round 8
// baseline (160.277 us; speedup 1.0000x reference)
//
#include <hip/hip_runtime.h>

// VarlenAttention MI355X — round 8: split-K load balancing. Fixed-max softmax
// makes (o,l) partials additive over key subsets -> grid (tile, head, slot of 4),
// each slot handles chunks j % 4 == s (max ~5 chunks vs 17 unbalanced).
// Partials atomicAdd'ed into fp32 O + Lacc; final normalize kernel divides.
// l computed via ones-column MFMA (row sums of P on the matrix pipe).
constexpr int NSEG = 8;
constexpr int H    = 16;
constexpr int D    = 64;
constexpr int BK   = 64;
constexpr int SPL  = 4;        // split slots per (tile, head)
constexpr int LDK  = D  + 8;
constexpr int LDV  = BK + 8;
constexpr int LDP  = BK + 8;

typedef __attribute__((ext_vector_type(8))) short short8v;
typedef __attribute__((ext_vector_type(4))) short short4v;
typedef __attribute__((ext_vector_type(4))) float floatx4;

__device__ inline short f2bf(float f) {  // RNE fp32 -> bf16
    union { float f; unsigned u; } x; x.f = f;
    unsigned r = x.u + 0x7FFFu + ((x.u >> 16) & 1u);
    return (short)(r >> 16);
}

// ---- pre-pass: Qb[h][t][d] (x0.125), Kb[h][t][d], Vb[h][d][t], segArr[t] ---
__global__ __launch_bounds__(256)
void prepass_qkv(const float* __restrict__ Q, const float* __restrict__ K,
                 const float* __restrict__ V, const int* __restrict__ cuk,
                 short* __restrict__ Qb, short* __restrict__ Kb,
                 short* __restrict__ Vb, int* __restrict__ segArr, int T)
{
    __shared__ short sVT[D][LDK];
    const int tid = threadIdx.x;
    const int nCh = T >> 6;
    const int h  = blockIdx.x / nCh;
    const int t0 = (blockIdx.x % nCh) << 6;
    #pragma unroll
    for (int it = 0; it < 2; ++it) {
        int s  = tid + it * 256;
        int tl = s >> 3;
        int d8 = (s & 7) << 3;
        int t  = t0 + tl;
        const float* kp = K + ((size_t)t * H + h) * D + d8;
        float4 a = *(const float4*)kp;
        float4 b = *(const float4*)(kp + 4);
        short8v ks;
        ks[0]=f2bf(a.x); ks[1]=f2bf(a.y); ks[2]=f2bf(a.z); ks[3]=f2bf(a.w);
        ks[4]=f2bf(b.x); ks[5]=f2bf(b.y); ks[6]=f2bf(b.z); ks[7]=f2bf(b.w);
        *(short8v*)&Kb[((size_t)h * T + t) * D + d8] = ks;
        const float* qp = Q + ((size_t)t * H + h) * D + d8;
        float4 qa = *(const float4*)qp;
        float4 qb = *(const float4*)(qp + 4);
        short8v qs;
        qs[0]=f2bf(qa.x*0.125f); qs[1]=f2bf(qa.y*0.125f);
        qs[2]=f2bf(qa.z*0.125f); qs[3]=f2bf(qa.w*0.125f);
        qs[4]=f2bf(qb.x*0.125f); qs[5]=f2bf(qb.y*0.125f);
        qs[6]=f2bf(qb.z*0.125f); qs[7]=f2bf(qb.w*0.125f);
        *(short8v*)&Qb[((size_t)h * T + t) * D + d8] = qs;
        const float* vp = V + ((size_t)t * H + h) * D + d8;
        float4 c = *(const float4*)vp;
        float4 e = *(const float4*)(vp + 4);
        sVT[d8+0][tl]=f2bf(c.x); sVT[d8+1][tl]=f2bf(c.y);
        sVT[d8+2][tl]=f2bf(c.z); sVT[d8+3][tl]=f2bf(c.w);
        sVT[d8+4][tl]=f2bf(e.x); sVT[d8+5][tl]=f2bf(e.y);
        sVT[d8+6][tl]=f2bf(e.z); sVT[d8+7][tl]=f2bf(e.w);
    }
    if (h == 0 && tid < 64) {
        int t = t0 + tid;
        int s = 0;
        #pragma unroll
        for (int i = 1; i < NSEG; ++i) s += (t >= cuk[i]) ? 1 : 0;
        segArr[t] = s;
    }
    __syncthreads();
    #pragma unroll
    for (int it = 0; it < 2; ++it) {
        int s  = tid + it * 256;
        int d  = s >> 3;
        int t8 = (s & 7) << 3;
        *(short8v*)&Vb[((size_t)h * D + d) * T + t0 + t8] = *(const short8v*)&sVT[d][t8];
    }
}

// ---- main: split-K flash, r5 chunk structure, atomic partial combine -------
__global__ __launch_bounds__(256)
void varlen_attn7(const short* __restrict__ Qb,
                  const short* __restrict__ Kb, const short* __restrict__ Vb,
                  const int* __restrict__ segArr,
                  const int* __restrict__ cuq, const int* __restrict__ cuk,
                  float* __restrict__ O, float* __restrict__ Lacc, int T)
{
    __shared__ short sK[BK][LDK];        // (key, d)
    __shared__ short sVT[D][LDV];        // (d, key)
    __shared__ short sP[4][16][LDP];     // per-wave (qrow, key)

    const int tid  = threadIdx.x;
    const int lane = tid & 63;
    const int w    = tid >> 6;
    const int quad = lane >> 4;
    const int l15  = lane & 15;
    const int slot = blockIdx.x & (SPL - 1);
    const int th   = blockIdx.x >> 2;    // (tile*H + h)
    const int h    = th % H;
    const int t0   = (th / H) * 64;

    // cu values — uniform -> scalar loads
    int q1 = cuq[1], q2 = cuq[2], q3 = cuq[3], q4 = cuq[4],
        q5 = cuq[5], q6 = cuq[6], q7 = cuq[7];
    int c0 = cuk[0], c1 = cuk[1], c2 = cuk[2], c3 = cuk[3], c4 = cuk[4],
        c5 = cuk[5], c6 = cuk[6], c7 = cuk[7], c8 = cuk[8];

    int sA = (t0>=q1)+(t0>=q2)+(t0>=q3)+(t0>=q4)+(t0>=q5)+(t0>=q6)+(t0>=q7);
    int tBr = t0 + 63;
    int sB = (tBr>=q1)+(tBr>=q2)+(tBr>=q3)+(tBr>=q4)+(tBr>=q5)+(tBr>=q6)+(tBr>=q7);
    int k_start = c0;
    k_start = (sA>0)?c1:k_start; k_start = (sA>1)?c2:k_start;
    k_start = (sA>2)?c3:k_start; k_start = (sA>3)?c4:k_start;
    k_start = (sA>4)?c5:k_start; k_start = (sA>5)?c6:k_start;
    k_start = (sA>6)?c7:k_start;
    int k_end = c1;
    k_end = (sB>0)?c2:k_end; k_end = (sB>1)?c3:k_end;
    k_end = (sB>2)?c4:k_end; k_end = (sB>3)?c5:k_end;
    k_end = (sB>4)?c6:k_end; k_end = (sB>5)?c7:k_end;
    k_end = (sB>6)?c8:k_end;

    const int kc0 = k_start & ~(BK - 1);
    const int n   = (k_end - kc0 + BK - 1) >> 6;   // total 64-chunks
    if (slot >= n) return;                          // empty slot: no work at all

    // q segment ids (C/D rows 16w + quad*4 + r)
    int segq[4];
    #pragma unroll
    for (int r = 0; r < 4; ++r) {
        int t = t0 + 16 * w + quad * 4 + r;
        segq[r] = (t>=q1)+(t>=q2)+(t>=q3)+(t>=q4)+(t>=q5)+(t>=q6)+(t>=q7);
    }

    // Q A-fragments: direct b128 loads from pre-scaled bf16 Qb
    const short* qbp = Qb + ((size_t)h * T + t0 + 16 * w + l15) * D + quad * 8;
    short8v aQ0 = *(const short8v*)(qbp);
    short8v aQ1 = *(const short8v*)(qbp + 32);

    const short* Kbh = Kb + (size_t)h * T * D;
    const short* Vbh = Vb + (size_t)h * D * T;
    const int key0 = tid >> 3;        // 0..31
    const int e8   = (tid & 7) << 3;  // 0..56

    // ones B-frag (bf16 1.0) for the P row-sum MFMA
    short8v ones;
    #pragma unroll
    for (int i = 0; i < 8; ++i) ones[i] = (short)0x3F80;

    floatx4 o[4];
    #pragma unroll
    for (int nt = 0; nt < 4; ++nt) o[nt] = (floatx4){0.f, 0.f, 0.f, 0.f};
    floatx4 lacc = (floatx4){0.f, 0.f, 0.f, 0.f};

    // initial prefetch (chunk j = slot)
    short8v rb0, rb1, rb2, rb3;
    int sgC[4], sgN[4];
    {
        int kc = kc0 + (slot << 6);
        rb0 = *(const short8v*)(Kbh + (size_t)(kc + key0)      * D + e8);
        rb1 = *(const short8v*)(Kbh + (size_t)(kc + 32 + key0) * D + e8);
        rb2 = *(const short8v*)(Vbh + (size_t)key0        * T + kc + e8);
        rb3 = *(const short8v*)(Vbh + (size_t)(32 + key0) * T + kc + e8);
        #pragma unroll
        for (int nt = 0; nt < 4; ++nt) sgC[nt] = segArr[kc + nt * 16 + l15];
    }

    for (int j = slot; j < n; j += SPL) {
        __syncthreads();   // previous chunk's LDS reads complete
        *(short8v*)&sK[key0][e8]       = rb0;
        *(short8v*)&sK[32 + key0][e8]  = rb1;
        *(short8v*)&sVT[key0][e8]      = rb2;
        *(short8v*)&sVT[32 + key0][e8] = rb3;
        __syncthreads();

        // fire next chunk's loads (consumed next iteration)
        int jn = j + SPL;
        if (jn < n) {
            int kn = kc0 + (jn << 6);
            rb0 = *(const short8v*)(Kbh + (size_t)(kn + key0)      * D + e8);
            rb1 = *(const short8v*)(Kbh + (size_t)(kn + 32 + key0) * D + e8);
            rb2 = *(const short8v*)(Vbh + (size_t)key0        * T + kn + e8);
            rb3 = *(const short8v*)(Vbh + (size_t)(32 + key0) * T + kn + e8);
            #pragma unroll
            for (int nt = 0; nt < 4; ++nt) sgN[nt] = segArr[kn + nt * 16 + l15];
        }

        // ---- S = Q K^T, fixed-max shift (-8) folded into C-init ----
        floatx4 sacc[4];
        #pragma unroll
        for (int nt = 0; nt < 4; ++nt) {
            sacc[nt] = (floatx4){-8.f, -8.f, -8.f, -8.f};
            short8v b0 = *(const short8v*)&sK[nt * 16 + l15][quad * 8];
            short8v b1 = *(const short8v*)&sK[nt * 16 + l15][32 + quad * 8];
            sacc[nt] = __builtin_amdgcn_mfma_f32_16x16x32_bf16(aQ0, b0, sacc[nt], 0, 0, 0);
            sacc[nt] = __builtin_amdgcn_mfma_f32_16x16x32_bf16(aQ1, b1, sacc[nt], 0, 0, 0);
        }

        // ---- mask + exp, write P (wave-private sP; l comes from ones-MFMA) --
        #pragma unroll
        for (int nt = 0; nt < 4; ++nt)
            #pragma unroll
            for (int r = 0; r < 4; ++r) {
                float sc = (sgC[nt] == segq[r]) ? sacc[nt][r] : -1e30f;
                float p  = __expf(sc);           // masked -> exactly 0
                sP[w][quad * 4 + r][nt * 16 + l15] = f2bf(p);
            }
        #pragma unroll
        for (int nt = 0; nt < 4; ++nt) sgC[nt] = sgN[nt];

        // ---- P A-frags (in-wave LDS roundtrip) ----
        short8v aP0 = *(const short8v*)&sP[w][l15][quad * 8];
        short8v aP1 = *(const short8v*)&sP[w][l15][32 + quad * 8];

        // ---- O += P V; l += P . 1 (row sums, dup across l15) ----
        #pragma unroll
        for (int nt = 0; nt < 4; ++nt) {
            short8v v0 = *(const short8v*)&sVT[nt * 16 + l15][quad * 8];
            short8v v1 = *(const short8v*)&sVT[nt * 16 + l15][32 + quad * 8];
            o[nt] = __builtin_amdgcn_mfma_f32_16x16x32_bf16(aP0, v0, o[nt], 0, 0, 0);
            o[nt] = __builtin_amdgcn_mfma_f32_16x16x32_bf16(aP1, v1, o[nt], 0, 0, 0);
        }
        lacc = __builtin_amdgcn_mfma_f32_16x16x32_bf16(aP0, ones, lacc, 0, 0, 0);
        lacc = __builtin_amdgcn_mfma_f32_16x16x32_bf16(aP1, ones, lacc, 0, 0, 0);
    }

    // ---- epilogue: atomic partial combine (additive under fixed-max) ----
    #pragma unroll
    for (int r = 0; r < 4; ++r) {
        int row = t0 + 16 * w + quad * 4 + r;
        if (l15 == 0) atomicAdd(&Lacc[row * H + h], lacc[r]);
        float* op = O + ((size_t)row * H + h) * D + l15;
        #pragma unroll
        for (int nt = 0; nt < 4; ++nt)
            atomicAdd(op + nt * 16, o[nt][r]);
    }
}

// ---- normalize: O[t][h][d] /= Lacc[t][h] ----------------------------------
__global__ __launch_bounds__(256)
void normalize_o(float* __restrict__ O, const float* __restrict__ Lacc, int total4)
{
    int i = blockIdx.x * 256 + threadIdx.x;
    if (i < total4) {
        float inv = 1.0f / Lacc[i >> 4];       // D/4 = 16 float4 per (t,h) row
        float4* p = (float4*)O + i;
        float4 v = *p;
        v.x *= inv; v.y *= inv; v.z *= inv; v.w *= inv;
        *p = v;
    }
}

// ---------------- fallback (self-contained, LDS-staged, any T) --------------
__global__ __launch_bounds__(256)
void varlen_attn_fb(const float* __restrict__ Q, const float* __restrict__ K,
                    const float* __restrict__ V, const int* __restrict__ cuq,
                    const int* __restrict__ cuk, float* __restrict__ O, int T)
{
    __shared__ short sKf[64][LDK];
    __shared__ short sVf[D][72];
    __shared__ short sPf[4][16][72];
    __shared__ int   sSegK[64];
    __shared__ int   sCuQ[NSEG + 1], sCuK[NSEG + 1];

    const int tid  = threadIdx.x;
    const int lane = tid & 63;
    const int w    = tid >> 6;
    const int quad = lane >> 4;
    const int l15  = lane & 15;
    const int h    = blockIdx.x % H;
    const int t0   = (blockIdx.x / H) * 64;

    if (tid <= NSEG) { sCuQ[tid] = cuq[tid]; sCuK[tid] = cuk[tid]; }
    __syncthreads();

    int qrow = t0 + 16 * w + l15; if (qrow >= T) qrow = T - 1;
    const float* qp = Q + ((size_t)qrow * H + h) * D + quad * 8;
    short8v aQ0, aQ1;
    {
        float4 a = *(const float4*)(qp);
        float4 b = *(const float4*)(qp + 4);
        float4 c = *(const float4*)(qp + 32);
        float4 e = *(const float4*)(qp + 36);
        aQ0[0]=f2bf(a.x*0.125f); aQ0[1]=f2bf(a.y*0.125f);
        aQ0[2]=f2bf(a.z*0.125f); aQ0[3]=f2bf(a.w*0.125f);
        aQ0[4]=f2bf(b.x*0.125f); aQ0[5]=f2bf(b.y*0.125f);
        aQ0[6]=f2bf(b.z*0.125f); aQ0[7]=f2bf(b.w*0.125f);
        aQ1[0]=f2bf(c.x*0.125f); aQ1[1]=f2bf(c.y*0.125f);
        aQ1[2]=f2bf(c.z*0.125f); aQ1[3]=f2bf(c.w*0.125f);
        aQ1[4]=f2bf(e.x*0.125f); aQ1[5]=f2bf(e.y*0.125f);
        aQ1[6]=f2bf(e.z*0.125f); aQ1[7]=f2bf(e.w*0.125f);
    }

    int segq[4];
    #pragma unroll
    for (int r = 0; r < 4; ++r) {
        int t = t0 + 16 * w + quad * 4 + r; if (t >= T) t = T - 1;
        int s = 0;
        while (s < NSEG - 1 && t >= sCuQ[s + 1]) ++s;
        segq[r] = s;
    }
    int k_start, k_end;
    {
        int tA = t0; if (tA >= T) tA = T - 1;
        int tB = t0 + 63; if (tB >= T) tB = T - 1;
        int sA2 = 0; while (sA2 < NSEG - 1 && tA >= sCuQ[sA2 + 1]) ++sA2;
        int sB2 = 0; while (sB2 < NSEG - 1 && tB >= sCuQ[sB2 + 1]) ++sB2;
        k_start = sCuK[sA2];
        k_end   = sCuK[sB2 + 1];
    }

    floatx4 o[4];
    #pragma unroll
    for (int nt = 0; nt < 4; ++nt) o[nt] = (floatx4){0.f, 0.f, 0.f, 0.f};
    float l_r[4] = {0.f, 0.f, 0.f, 0.f};

    for (int kc = k_start; kc < k_end; kc += 64) {
        __syncthreads();
        for (int i = tid; i < 64 * D / 4; i += 256) {
            int k = i >> 4;
            int c = (i & 15) << 2;
            int kt = kc + k;
            float4 kv = {0,0,0,0}, vv = {0,0,0,0};
            if (kt < k_end) {
                kv = *(const float4*)&K[((size_t)kt * H + h) * D + c];
                vv = *(const float4*)&V[((size_t)kt * H + h) * D + c];
            }
            short4v ks;
            ks.x=f2bf(kv.x); ks.y=f2bf(kv.y); ks.z=f2bf(kv.z); ks.w=f2bf(kv.w);
            *(short4v*)&sKf[k][c] = ks;
            sVf[c+0][k]=f2bf(vv.x); sVf[c+1][k]=f2bf(vv.y);
            sVf[c+2][k]=f2bf(vv.z); sVf[c+3][k]=f2bf(vv.w);
        }
        if (tid < 64) {
            int kt = kc + tid;
            int s = -1;
            if (kt < k_end) { s = 0; while (s < NSEG - 1 && kt >= sCuK[s + 1]) ++s; }
            sSegK[tid] = s;
        }
        __syncthreads();

        floatx4 sacc[4];
        #pragma unroll
        for (int nt = 0; nt < 4; ++nt) {
            sacc[nt] = (floatx4){-8.f, -8.f, -8.f, -8.f};
            short8v b0 = *(const short8v*)&sKf[nt * 16 + l15][quad * 8];
            short8v b1 = *(const short8v*)&sKf[nt * 16 + l15][32 + quad * 8];
            sacc[nt] = __builtin_amdgcn_mfma_f32_16x16x32_bf16(aQ0, b0, sacc[nt], 0, 0, 0);
            sacc[nt] = __builtin_amdgcn_mfma_f32_16x16x32_bf16(aQ1, b1, sacc[nt], 0, 0, 0);
        }
        #pragma unroll
        for (int nt = 0; nt < 4; ++nt) {
            int segk = sSegK[nt * 16 + l15];
            #pragma unroll
            for (int r = 0; r < 4; ++r) {
                float sc = (segk == segq[r]) ? sacc[nt][r] : -1e30f;
                float p  = __expf(sc);
                l_r[r] += p;
                sPf[w][quad * 4 + r][nt * 16 + l15] = f2bf(p);
            }
        }
        short8v aP0 = *(const short8v*)&sPf[w][l15][quad * 8];
        short8v aP1 = *(const short8v*)&sPf[w][l15][32 + quad * 8];
        #pragma unroll
        for (int nt = 0; nt < 4; ++nt) {
            short8v b0 = *(const short8v*)&sVf[nt * 16 + l15][quad * 8];
            short8v b1 = *(const short8v*)&sVf[nt * 16 + l15][32 + quad * 8];
            o[nt] = __builtin_amdgcn_mfma_f32_16x16x32_bf16(aP0, b0, o[nt], 0, 0, 0);
            o[nt] = __builtin_amdgcn_mfma_f32_16x16x32_bf16(aP1, b1, o[nt], 0, 0, 0);
        }
    }

    #pragma unroll
    for (int off = 1; off < 16; off <<= 1)
        #pragma unroll
        for (int r = 0; r < 4; ++r)
            l_r[r] += __shfl_xor(l_r[r], off);

    #pragma unroll
    for (int r = 0; r < 4; ++r) {
        int trow = t0 + 16 * w + quad * 4 + r;
        if (trow < T) {
            float linv = 1.0f / l_r[r];
            float* op = O + ((size_t)trow * H + h) * D + l15;
            #pragma unroll
            for (int nt = 0; nt < 4; ++nt)
                op[nt * 16] = o[nt][r] * linv;
        }
    }
}

extern "C" void kernel_launch(void* const* d_in, const int* in_sizes, int n_in,
                              void* d_out, int out_size, void* d_ws, size_t ws_size,
                              hipStream_t stream) {
    const float* Q = (const float*)d_in[0];
    const float* K = (const float*)d_in[1];
    const float* V = (const float*)d_in[2];
    const int* cuq = (const int*)d_in[3];
    const int* cuk = (const int*)d_in[4];
    float* O = (float*)d_out;

    int T = in_sizes[0] / (H * D);
    size_t need = (size_t)3 * H * T * D * sizeof(short)
                + (size_t)T * sizeof(int) + (size_t)T * H * sizeof(float);

    if (ws_size >= need && (T & 63) == 0) {
        short* Qb = (short*)d_ws;
        short* Kb = Qb + (size_t)H * T * D;
        short* Vb = Kb + (size_t)H * T * D;
        int*   segArr = (int*)(Vb + (size_t)H * T * D);
        float* Lacc   = (float*)(segArr + T);

        hipLaunchKernelGGL(prepass_qkv, dim3(H * (T >> 6)), dim3(256), 0, stream,
                           Q, K, V, cuk, Qb, Kb, Vb, segArr, T);
        hipMemsetAsync(O, 0, (size_t)out_size * sizeof(float), stream);
        hipMemsetAsync(Lacc, 0, (size_t)T * H * sizeof(float), stream);
        hipLaunchKernelGGL(varlen_attn7, dim3((T / 64) * H * SPL), dim3(256), 0, stream,
                           Qb, Kb, Vb, segArr, cuq, cuk, O, Lacc, T);
        int total4 = T * H * D / 4;
        hipLaunchKernelGGL(normalize_o, dim3((total4 + 255) / 256), dim3(256), 0, stream,
                           O, Lacc, total4);
    } else {
        int nQT = (T + 63) / 64;
        hipLaunchKernelGGL(varlen_attn_fb, dim3(nQT * H), dim3(256), 0, stream,
                           Q, K, V, cuq, cuk, O, T);
    }
}

// Round 9
// 136.142 us; speedup vs baseline: 1.1773x; 1.1773x over previous
//
#include <hip/hip_runtime.h>

// VarlenAttention MI355X — round 9: r5 kernel + ADAPTIVE split-K.
// Blocks with n<=THR chunks run the plain r5 path (normalized plain store,
// Lacc=1). Long tiles (n>THR) split into 2 contiguous halves; their (o,l)
// partials are additive under fixed-max softmax -> fp32 atomicAdd combine,
// then a normalize kernel divides by Lacc. l via ones-column MFMA.
constexpr int NSEG = 8;
constexpr int H    = 16;
constexpr int D    = 64;
constexpr int BK   = 64;
constexpr int THR  = 9;        // split tiles with more than THR chunks
constexpr int LDK  = D  + 8;
constexpr int LDV  = BK + 8;
constexpr int LDP  = BK + 8;

typedef __attribute__((ext_vector_type(8))) short short8v;
typedef __attribute__((ext_vector_type(4))) short short4v;
typedef __attribute__((ext_vector_type(4))) float floatx4;

__device__ inline short f2bf(float f) {  // RNE fp32 -> bf16
    union { float f; unsigned u; } x; x.f = f;
    unsigned r = x.u + 0x7FFFu + ((x.u >> 16) & 1u);
    return (short)(r >> 16);
}

// ---- pre-pass: Qb[h][t][d] (x0.125), Kb[h][t][d], Vb[h][d][t], segArr, Lacc=0
__global__ __launch_bounds__(256)
void prepass_qkv(const float* __restrict__ Q, const float* __restrict__ K,
                 const float* __restrict__ V, const int* __restrict__ cuk,
                 short* __restrict__ Qb, short* __restrict__ Kb,
                 short* __restrict__ Vb, int* __restrict__ segArr,
                 float* __restrict__ Lacc, int T)
{
    __shared__ short sVT[D][LDK];
    const int tid = threadIdx.x;
    const int nCh = T >> 6;
    const int h  = blockIdx.x / nCh;
    const int t0 = (blockIdx.x % nCh) << 6;
    #pragma unroll
    for (int it = 0; it < 2; ++it) {
        int s  = tid + it * 256;
        int tl = s >> 3;
        int d8 = (s & 7) << 3;
        int t  = t0 + tl;
        const float* kp = K + ((size_t)t * H + h) * D + d8;
        float4 a = *(const float4*)kp;
        float4 b = *(const float4*)(kp + 4);
        short8v ks;
        ks[0]=f2bf(a.x); ks[1]=f2bf(a.y); ks[2]=f2bf(a.z); ks[3]=f2bf(a.w);
        ks[4]=f2bf(b.x); ks[5]=f2bf(b.y); ks[6]=f2bf(b.z); ks[7]=f2bf(b.w);
        *(short8v*)&Kb[((size_t)h * T + t) * D + d8] = ks;
        const float* qp = Q + ((size_t)t * H + h) * D + d8;
        float4 qa = *(const float4*)qp;
        float4 qb = *(const float4*)(qp + 4);
        short8v qs;
        qs[0]=f2bf(qa.x*0.125f); qs[1]=f2bf(qa.y*0.125f);
        qs[2]=f2bf(qa.z*0.125f); qs[3]=f2bf(qa.w*0.125f);
        qs[4]=f2bf(qb.x*0.125f); qs[5]=f2bf(qb.y*0.125f);
        qs[6]=f2bf(qb.z*0.125f); qs[7]=f2bf(qb.w*0.125f);
        *(short8v*)&Qb[((size_t)h * T + t) * D + d8] = qs;
        const float* vp = V + ((size_t)t * H + h) * D + d8;
        float4 c = *(const float4*)vp;
        float4 e = *(const float4*)(vp + 4);
        sVT[d8+0][tl]=f2bf(c.x); sVT[d8+1][tl]=f2bf(c.y);
        sVT[d8+2][tl]=f2bf(c.z); sVT[d8+3][tl]=f2bf(c.w);
        sVT[d8+4][tl]=f2bf(e.x); sVT[d8+5][tl]=f2bf(e.y);
        sVT[d8+6][tl]=f2bf(e.z); sVT[d8+7][tl]=f2bf(e.w);
    }
    if (tid < 64) {
        int t = t0 + tid;
        Lacc[(size_t)t * H + h] = 0.0f;       // zeroed ahead of main's atomics
        if (h == 0) {
            int s = 0;
            #pragma unroll
            for (int i = 1; i < NSEG; ++i) s += (t >= cuk[i]) ? 1 : 0;
            segArr[t] = s;
        }
    }
    __syncthreads();
    #pragma unroll
    for (int it = 0; it < 2; ++it) {
        int s  = tid + it * 256;
        int d  = s >> 3;
        int t8 = (s & 7) << 3;
        *(short8v*)&Vb[((size_t)h * D + d) * T + t0 + t8] = *(const short8v*)&sVT[d][t8];
    }
}

// ---- main: r5 structure + adaptive 2-way split of long tiles ---------------
__global__ __launch_bounds__(256)
void varlen_attn8(const short* __restrict__ Qb,
                  const short* __restrict__ Kb, const short* __restrict__ Vb,
                  const int* __restrict__ segArr,
                  const int* __restrict__ cuq, const int* __restrict__ cuk,
                  float* __restrict__ O, float* __restrict__ Lacc, int T)
{
    __shared__ short sK[BK][LDK];        // (key, d)
    __shared__ short sVT[D][LDV];        // (d, key)
    __shared__ short sP[4][16][LDP];     // per-wave (qrow, key)

    const int tid  = threadIdx.x;
    const int lane = tid & 63;
    const int w    = tid >> 6;
    const int quad = lane >> 4;
    const int l15  = lane & 15;
    const int slot = blockIdx.x & 1;
    const int th   = blockIdx.x >> 1;
    const int h    = th % H;
    const int t0   = (th / H) * 64;

    // cu values — uniform -> scalar loads
    int q1 = cuq[1], q2 = cuq[2], q3 = cuq[3], q4 = cuq[4],
        q5 = cuq[5], q6 = cuq[6], q7 = cuq[7];
    int c0 = cuk[0], c1 = cuk[1], c2 = cuk[2], c3 = cuk[3], c4 = cuk[4],
        c5 = cuk[5], c6 = cuk[6], c7 = cuk[7], c8 = cuk[8];

    int sA = (t0>=q1)+(t0>=q2)+(t0>=q3)+(t0>=q4)+(t0>=q5)+(t0>=q6)+(t0>=q7);
    int tBr = t0 + 63;
    int sB = (tBr>=q1)+(tBr>=q2)+(tBr>=q3)+(tBr>=q4)+(tBr>=q5)+(tBr>=q6)+(tBr>=q7);
    int k_start = c0;
    k_start = (sA>0)?c1:k_start; k_start = (sA>1)?c2:k_start;
    k_start = (sA>2)?c3:k_start; k_start = (sA>3)?c4:k_start;
    k_start = (sA>4)?c5:k_start; k_start = (sA>5)?c6:k_start;
    k_start = (sA>6)?c7:k_start;
    int k_end = c1;
    k_end = (sB>0)?c2:k_end; k_end = (sB>1)?c3:k_end;
    k_end = (sB>2)?c4:k_end; k_end = (sB>3)?c5:k_end;
    k_end = (sB>4)?c6:k_end; k_end = (sB>5)?c7:k_end;
    k_end = (sB>6)?c8:k_end;

    const int kc0 = k_start & ~(BK - 1);
    const int n   = (k_end - kc0 + BK - 1) >> 6;   // total 64-key chunks
    const bool split = n > THR;
    if (!split && slot == 1) return;               // short tile: slot 1 idle

    int j0 = 0, j1 = n;
    if (split) {
        int half = (n + 1) >> 1;
        j0 = slot * half;
        j1 = min(n, j0 + half);
    }

    // q segment ids (C/D rows 16w + quad*4 + r)
    int segq[4];
    #pragma unroll
    for (int r = 0; r < 4; ++r) {
        int t = t0 + 16 * w + quad * 4 + r;
        segq[r] = (t>=q1)+(t>=q2)+(t>=q3)+(t>=q4)+(t>=q5)+(t>=q6)+(t>=q7);
    }

    // Q A-fragments: direct b128 loads from pre-scaled bf16 Qb
    const short* qbp = Qb + ((size_t)h * T + t0 + 16 * w + l15) * D + quad * 8;
    short8v aQ0 = *(const short8v*)(qbp);
    short8v aQ1 = *(const short8v*)(qbp + 32);

    const short* Kbh = Kb + (size_t)h * T * D;
    const short* Vbh = Vb + (size_t)h * D * T;
    const int key0 = tid >> 3;        // 0..31
    const int e8   = (tid & 7) << 3;  // 0..56

    // ones B-frag (bf16 1.0) for the P row-sum MFMA
    short8v ones;
    #pragma unroll
    for (int i = 0; i < 8; ++i) ones[i] = (short)0x3F80;

    floatx4 o[4];
    #pragma unroll
    for (int nt = 0; nt < 4; ++nt) o[nt] = (floatx4){0.f, 0.f, 0.f, 0.f};
    floatx4 lacc = (floatx4){0.f, 0.f, 0.f, 0.f};

    // initial prefetch (chunk j0)
    short8v rb0, rb1, rb2, rb3;
    int sgC[4], sgN[4];
    {
        int kc = kc0 + (j0 << 6);
        rb0 = *(const short8v*)(Kbh + (size_t)(kc + key0)      * D + e8);
        rb1 = *(const short8v*)(Kbh + (size_t)(kc + 32 + key0) * D + e8);
        rb2 = *(const short8v*)(Vbh + (size_t)key0        * T + kc + e8);
        rb3 = *(const short8v*)(Vbh + (size_t)(32 + key0) * T + kc + e8);
        #pragma unroll
        for (int nt = 0; nt < 4; ++nt) sgC[nt] = segArr[kc + nt * 16 + l15];
    }

    for (int j = j0; j < j1; ++j) {
        __syncthreads();   // previous chunk's LDS reads complete
        *(short8v*)&sK[key0][e8]       = rb0;
        *(short8v*)&sK[32 + key0][e8]  = rb1;
        *(short8v*)&sVT[key0][e8]      = rb2;
        *(short8v*)&sVT[32 + key0][e8] = rb3;
        __syncthreads();

        // fire next chunk's loads (consumed next iteration)
        if (j + 1 < j1) {
            int kn = kc0 + ((j + 1) << 6);
            rb0 = *(const short8v*)(Kbh + (size_t)(kn + key0)      * D + e8);
            rb1 = *(const short8v*)(Kbh + (size_t)(kn + 32 + key0) * D + e8);
            rb2 = *(const short8v*)(Vbh + (size_t)key0        * T + kn + e8);
            rb3 = *(const short8v*)(Vbh + (size_t)(32 + key0) * T + kn + e8);
            #pragma unroll
            for (int nt = 0; nt < 4; ++nt) sgN[nt] = segArr[kn + nt * 16 + l15];
        }

        // ---- S = Q K^T, fixed-max shift (-8) folded into C-init ----
        floatx4 sacc[4];
        #pragma unroll
        for (int nt = 0; nt < 4; ++nt) {
            sacc[nt] = (floatx4){-8.f, -8.f, -8.f, -8.f};
            short8v b0 = *(const short8v*)&sK[nt * 16 + l15][quad * 8];
            short8v b1 = *(const short8v*)&sK[nt * 16 + l15][32 + quad * 8];
            sacc[nt] = __builtin_amdgcn_mfma_f32_16x16x32_bf16(aQ0, b0, sacc[nt], 0, 0, 0);
            sacc[nt] = __builtin_amdgcn_mfma_f32_16x16x32_bf16(aQ1, b1, sacc[nt], 0, 0, 0);
        }

        // ---- mask + exp, write P (wave-private sP; l via ones-MFMA) ----
        #pragma unroll
        for (int nt = 0; nt < 4; ++nt)
            #pragma unroll
            for (int r = 0; r < 4; ++r) {
                float sc = (sgC[nt] == segq[r]) ? sacc[nt][r] : -1e30f;
                float p  = __expf(sc);           // masked -> exactly 0
                sP[w][quad * 4 + r][nt * 16 + l15] = f2bf(p);
            }
        #pragma unroll
        for (int nt = 0; nt < 4; ++nt) sgC[nt] = sgN[nt];

        // ---- P A-frags (in-wave LDS roundtrip) ----
        short8v aP0 = *(const short8v*)&sP[w][l15][quad * 8];
        short8v aP1 = *(const short8v*)&sP[w][l15][32 + quad * 8];

        // ---- O += P V; l += P . 1 ----
        #pragma unroll
        for (int nt = 0; nt < 4; ++nt) {
            short8v v0 = *(const short8v*)&sVT[nt * 16 + l15][quad * 8];
            short8v v1 = *(const short8v*)&sVT[nt * 16 + l15][32 + quad * 8];
            o[nt] = __builtin_amdgcn_mfma_f32_16x16x32_bf16(aP0, v0, o[nt], 0, 0, 0);
            o[nt] = __builtin_amdgcn_mfma_f32_16x16x32_bf16(aP1, v1, o[nt], 0, 0, 0);
        }
        lacc = __builtin_amdgcn_mfma_f32_16x16x32_bf16(aP0, ones, lacc, 0, 0, 0);
        lacc = __builtin_amdgcn_mfma_f32_16x16x32_bf16(aP1, ones, lacc, 0, 0, 0);
    }

    // ---- epilogue ----
    if (!split) {
        // normalized plain store; Lacc = 1 so normalize is a no-op
        #pragma unroll
        for (int r = 0; r < 4; ++r) {
            int row = t0 + 16 * w + quad * 4 + r;
            float linv = 1.0f / lacc[r];
            if (l15 == 0) Lacc[(size_t)row * H + h] = 1.0f;
            float* op = O + ((size_t)row * H + h) * D + l15;
            #pragma unroll
            for (int nt = 0; nt < 4; ++nt)
                op[nt * 16] = o[nt][r] * linv;
        }
    } else {
        // additive partials: atomic combine (O zeroed, Lacc zeroed in prepass)
        #pragma unroll
        for (int r = 0; r < 4; ++r) {
            int row = t0 + 16 * w + quad * 4 + r;
            if (l15 == 0) atomicAdd(&Lacc[(size_t)row * H + h], lacc[r]);
            float* op = O + ((size_t)row * H + h) * D + l15;
            #pragma unroll
            for (int nt = 0; nt < 4; ++nt)
                atomicAdd(op + nt * 16, o[nt][r]);
        }
    }
}

// ---- normalize: O[t][h][d] /= Lacc[t][h] (x1.0 no-op for unsplit rows) ----
__global__ __launch_bounds__(256)
void normalize_o(float* __restrict__ O, const float* __restrict__ Lacc, int total4)
{
    int i = blockIdx.x * 256 + threadIdx.x;
    if (i < total4) {
        float inv = 1.0f / Lacc[i >> 4];       // 16 float4 per (t,h) row
        float4* p = (float4*)O + i;
        float4 v = *p;
        v.x *= inv; v.y *= inv; v.z *= inv; v.w *= inv;
        *p = v;
    }
}

// ---------------- fallback (self-contained, LDS-staged, any T) --------------
__global__ __launch_bounds__(256)
void varlen_attn_fb(const float* __restrict__ Q, const float* __restrict__ K,
                    const float* __restrict__ V, const int* __restrict__ cuq,
                    const int* __restrict__ cuk, float* __restrict__ O, int T)
{
    __shared__ short sKf[64][LDK];
    __shared__ short sVf[D][72];
    __shared__ short sPf[4][16][72];
    __shared__ int   sSegK[64];
    __shared__ int   sCuQ[NSEG + 1], sCuK[NSEG + 1];

    const int tid  = threadIdx.x;
    const int lane = tid & 63;
    const int w    = tid >> 6;
    const int quad = lane >> 4;
    const int l15  = lane & 15;
    const int h    = blockIdx.x % H;
    const int t0   = (blockIdx.x / H) * 64;

    if (tid <= NSEG) { sCuQ[tid] = cuq[tid]; sCuK[tid] = cuk[tid]; }
    __syncthreads();

    int qrow = t0 + 16 * w + l15; if (qrow >= T) qrow = T - 1;
    const float* qp = Q + ((size_t)qrow * H + h) * D + quad * 8;
    short8v aQ0, aQ1;
    {
        float4 a = *(const float4*)(qp);
        float4 b = *(const float4*)(qp + 4);
        float4 c = *(const float4*)(qp + 32);
        float4 e = *(const float4*)(qp + 36);
        aQ0[0]=f2bf(a.x*0.125f); aQ0[1]=f2bf(a.y*0.125f);
        aQ0[2]=f2bf(a.z*0.125f); aQ0[3]=f2bf(a.w*0.125f);
        aQ0[4]=f2bf(b.x*0.125f); aQ0[5]=f2bf(b.y*0.125f);
        aQ0[6]=f2bf(b.z*0.125f); aQ0[7]=f2bf(b.w*0.125f);
        aQ1[0]=f2bf(c.x*0.125f); aQ1[1]=f2bf(c.y*0.125f);
        aQ1[2]=f2bf(c.z*0.125f); aQ1[3]=f2bf(c.w*0.125f);
        aQ1[4]=f2bf(e.x*0.125f); aQ1[5]=f2bf(e.y*0.125f);
        aQ1[6]=f2bf(e.z*0.125f); aQ1[7]=f2bf(e.w*0.125f);
    }

    int segq[4];
    #pragma unroll
    for (int r = 0; r < 4; ++r) {
        int t = t0 + 16 * w + quad * 4 + r; if (t >= T) t = T - 1;
        int s = 0;
        while (s < NSEG - 1 && t >= sCuQ[s + 1]) ++s;
        segq[r] = s;
    }
    int k_start, k_end;
    {
        int tA = t0; if (tA >= T) tA = T - 1;
        int tB = t0 + 63; if (tB >= T) tB = T - 1;
        int sA2 = 0; while (sA2 < NSEG - 1 && tA >= sCuQ[sA2 + 1]) ++sA2;
        int sB2 = 0; while (sB2 < NSEG - 1 && tB >= sCuQ[sB2 + 1]) ++sB2;
        k_start = sCuK[sA2];
        k_end   = sCuK[sB2 + 1];
    }

    floatx4 o[4];
    #pragma unroll
    for (int nt = 0; nt < 4; ++nt) o[nt] = (floatx4){0.f, 0.f, 0.f, 0.f};
    float l_r[4] = {0.f, 0.f, 0.f, 0.f};

    for (int kc = k_start; kc < k_end; kc += 64) {
        __syncthreads();
        for (int i = tid; i < 64 * D / 4; i += 256) {
            int k = i >> 4;
            int c = (i & 15) << 2;
            int kt = kc + k;
            float4 kv = {0,0,0,0}, vv = {0,0,0,0};
            if (kt < k_end) {
                kv = *(const float4*)&K[((size_t)kt * H + h) * D + c];
                vv = *(const float4*)&V[((size_t)kt * H + h) * D + c];
            }
            short4v ks;
            ks.x=f2bf(kv.x); ks.y=f2bf(kv.y); ks.z=f2bf(kv.z); ks.w=f2bf(kv.w);
            *(short4v*)&sKf[k][c] = ks;
            sVf[c+0][k]=f2bf(vv.x); sVf[c+1][k]=f2bf(vv.y);
            sVf[c+2][k]=f2bf(vv.z); sVf[c+3][k]=f2bf(vv.w);
        }
        if (tid < 64) {
            int kt = kc + tid;
            int s = -1;
            if (kt < k_end) { s = 0; while (s < NSEG - 1 && kt >= sCuK[s + 1]) ++s; }
            sSegK[tid] = s;
        }
        __syncthreads();

        floatx4 sacc[4];
        #pragma unroll
        for (int nt = 0; nt < 4; ++nt) {
            sacc[nt] = (floatx4){-8.f, -8.f, -8.f, -8.f};
            short8v b0 = *(const short8v*)&sKf[nt * 16 + l15][quad * 8];
            short8v b1 = *(const short8v*)&sKf[nt * 16 + l15][32 + quad * 8];
            sacc[nt] = __builtin_amdgcn_mfma_f32_16x16x32_bf16(aQ0, b0, sacc[nt], 0, 0, 0);
            sacc[nt] = __builtin_amdgcn_mfma_f32_16x16x32_bf16(aQ1, b1, sacc[nt], 0, 0, 0);
        }
        #pragma unroll
        for (int nt = 0; nt < 4; ++nt) {
            int segk = sSegK[nt * 16 + l15];
            #pragma unroll
            for (int r = 0; r < 4; ++r) {
                float sc = (segk == segq[r]) ? sacc[nt][r] : -1e30f;
                float p  = __expf(sc);
                l_r[r] += p;
                sPf[w][quad * 4 + r][nt * 16 + l15] = f2bf(p);
            }
        }
        short8v aP0 = *(const short8v*)&sPf[w][l15][quad * 8];
        short8v aP1 = *(const short8v*)&sPf[w][l15][32 + quad * 8];
        #pragma unroll
        for (int nt = 0; nt < 4; ++nt) {
            short8v b0 = *(const short8v*)&sVf[nt * 16 + l15][quad * 8];
            short8v b1 = *(const short8v*)&sVf[nt * 16 + l15][32 + quad * 8];
            o[nt] = __builtin_amdgcn_mfma_f32_16x16x32_bf16(aP0, b0, o[nt], 0, 0, 0);
            o[nt] = __builtin_amdgcn_mfma_f32_16x16x32_bf16(aP1, b1, o[nt], 0, 0, 0);
        }
    }

    #pragma unroll
    for (int off = 1; off < 16; off <<= 1)
        #pragma unroll
        for (int r = 0; r < 4; ++r)
            l_r[r] += __shfl_xor(l_r[r], off);

    #pragma unroll
    for (int r = 0; r < 4; ++r) {
        int trow = t0 + 16 * w + quad * 4 + r;
        if (trow < T) {
            float linv = 1.0f / l_r[r];
            float* op = O + ((size_t)trow * H + h) * D + l15;
            #pragma unroll
            for (int nt = 0; nt < 4; ++nt)
                op[nt * 16] = o[nt][r] * linv;
        }
    }
}

extern "C" void kernel_launch(void* const* d_in, const int* in_sizes, int n_in,
                              void* d_out, int out_size, void* d_ws, size_t ws_size,
                              hipStream_t stream) {
    const float* Q = (const float*)d_in[0];
    const float* K = (const float*)d_in[1];
    const float* V = (const float*)d_in[2];
    const int* cuq = (const int*)d_in[3];
    const int* cuk = (const int*)d_in[4];
    float* O = (float*)d_out;

    int T = in_sizes[0] / (H * D);
    size_t need = (size_t)3 * H * T * D * sizeof(short)
                + (size_t)T * sizeof(int) + (size_t)T * H * sizeof(float);

    if (ws_size >= need && (T & 63) == 0) {
        short* Qb = (short*)d_ws;
        short* Kb = Qb + (size_t)H * T * D;
        short* Vb = Kb + (size_t)H * T * D;
        int*   segArr = (int*)(Vb + (size_t)H * T * D);
        float* Lacc   = (float*)(segArr + T);

        hipMemsetAsync(O, 0, (size_t)out_size * sizeof(float), stream);
        hipLaunchKernelGGL(prepass_qkv, dim3(H * (T >> 6)), dim3(256), 0, stream,
                           Q, K, V, cuk, Qb, Kb, Vb, segArr, Lacc, T);
        hipLaunchKernelGGL(varlen_attn8, dim3((T / 64) * H * 2), dim3(256), 0, stream,
                           Qb, Kb, Vb, segArr, cuq, cuk, O, Lacc, T);
        int total4 = T * H * D / 4;
        hipLaunchKernelGGL(normalize_o, dim3((total4 + 255) / 256), dim3(256), 0, stream,
                           O, Lacc, total4);
    } else {
        int nQT = (T + 63) / 64;
        hipLaunchKernelGGL(varlen_attn_fb, dim3(nQT * H), dim3(256), 0, stream,
                           Q, K, V, cuq, cuk, O, T);
    }
}

// Round 10
// 124.223 us; speedup vs baseline: 1.2902x; 1.0960x over previous
//
#include <hip/hip_runtime.h>

// VarlenAttention MI355X — round 10: r5 structure (best-known: 4-wave blocks,
// BK=64, 2 barriers/chunk, register prefetch, 5 blocks/CU) + Qb bf16 prepass
// + l via ones-column MFMA (no VALU l-adds, no epilogue shuffles).
constexpr int NSEG = 8;
constexpr int H    = 16;
constexpr int D    = 64;
constexpr int BK   = 64;
constexpr int LDK  = D  + 8;
constexpr int LDV  = BK + 8;
constexpr int LDP  = BK + 8;

typedef __attribute__((ext_vector_type(8))) short short8v;
typedef __attribute__((ext_vector_type(4))) short short4v;
typedef __attribute__((ext_vector_type(4))) float floatx4;

__device__ inline short f2bf(float f) {  // RNE fp32 -> bf16
    union { float f; unsigned u; } x; x.f = f;
    unsigned r = x.u + 0x7FFFu + ((x.u >> 16) & 1u);
    return (short)(r >> 16);
}

// ---- pre-pass: Qb[h][t][d] (x0.125), Kb[h][t][d], Vb[h][d][t], segArr[t] ---
__global__ __launch_bounds__(256)
void prepass_qkv(const float* __restrict__ Q, const float* __restrict__ K,
                 const float* __restrict__ V, const int* __restrict__ cuk,
                 short* __restrict__ Qb, short* __restrict__ Kb,
                 short* __restrict__ Vb, int* __restrict__ segArr, int T)
{
    __shared__ short sVT[D][LDK];
    const int tid = threadIdx.x;
    const int nCh = T >> 6;
    const int h  = blockIdx.x / nCh;
    const int t0 = (blockIdx.x % nCh) << 6;
    #pragma unroll
    for (int it = 0; it < 2; ++it) {
        int s  = tid + it * 256;
        int tl = s >> 3;
        int d8 = (s & 7) << 3;
        int t  = t0 + tl;
        const float* kp = K + ((size_t)t * H + h) * D + d8;
        float4 a = *(const float4*)kp;
        float4 b = *(const float4*)(kp + 4);
        short8v ks;
        ks[0]=f2bf(a.x); ks[1]=f2bf(a.y); ks[2]=f2bf(a.z); ks[3]=f2bf(a.w);
        ks[4]=f2bf(b.x); ks[5]=f2bf(b.y); ks[6]=f2bf(b.z); ks[7]=f2bf(b.w);
        *(short8v*)&Kb[((size_t)h * T + t) * D + d8] = ks;
        const float* qp = Q + ((size_t)t * H + h) * D + d8;
        float4 qa = *(const float4*)qp;
        float4 qb = *(const float4*)(qp + 4);
        short8v qs;
        qs[0]=f2bf(qa.x*0.125f); qs[1]=f2bf(qa.y*0.125f);
        qs[2]=f2bf(qa.z*0.125f); qs[3]=f2bf(qa.w*0.125f);
        qs[4]=f2bf(qb.x*0.125f); qs[5]=f2bf(qb.y*0.125f);
        qs[6]=f2bf(qb.z*0.125f); qs[7]=f2bf(qb.w*0.125f);
        *(short8v*)&Qb[((size_t)h * T + t) * D + d8] = qs;
        const float* vp = V + ((size_t)t * H + h) * D + d8;
        float4 c = *(const float4*)vp;
        float4 e = *(const float4*)(vp + 4);
        sVT[d8+0][tl]=f2bf(c.x); sVT[d8+1][tl]=f2bf(c.y);
        sVT[d8+2][tl]=f2bf(c.z); sVT[d8+3][tl]=f2bf(c.w);
        sVT[d8+4][tl]=f2bf(e.x); sVT[d8+5][tl]=f2bf(e.y);
        sVT[d8+6][tl]=f2bf(e.z); sVT[d8+7][tl]=f2bf(e.w);
    }
    if (h == 0 && tid < 64) {
        int t = t0 + tid;
        int s = 0;
        #pragma unroll
        for (int i = 1; i < NSEG; ++i) s += (t >= cuk[i]) ? 1 : 0;
        segArr[t] = s;
    }
    __syncthreads();
    #pragma unroll
    for (int it = 0; it < 2; ++it) {
        int s  = tid + it * 256;
        int d  = s >> 3;
        int t8 = (s & 7) << 3;
        *(short8v*)&Vb[((size_t)h * D + d) * T + t0 + t8] = *(const short8v*)&sVT[d][t8];
    }
}

// ---- main: r5 structure + Qb + ones-MFMA l ---------------------------------
__global__ __launch_bounds__(256)
void varlen_attn9(const short* __restrict__ Qb,
                  const short* __restrict__ Kb, const short* __restrict__ Vb,
                  const int* __restrict__ segArr,
                  const int* __restrict__ cuq, const int* __restrict__ cuk,
                  float* __restrict__ O, int T)
{
    __shared__ short sK[BK][LDK];        // (key, d)
    __shared__ short sVT[D][LDV];        // (d, key)
    __shared__ short sP[4][16][LDP];     // per-wave (qrow, key)

    const int tid  = threadIdx.x;
    const int lane = tid & 63;
    const int w    = tid >> 6;
    const int quad = lane >> 4;
    const int l15  = lane & 15;
    const int h    = blockIdx.x % H;
    const int t0   = (blockIdx.x / H) * 64;

    // cu values — uniform -> scalar loads
    int q1 = cuq[1], q2 = cuq[2], q3 = cuq[3], q4 = cuq[4],
        q5 = cuq[5], q6 = cuq[6], q7 = cuq[7];
    int c0 = cuk[0], c1 = cuk[1], c2 = cuk[2], c3 = cuk[3], c4 = cuk[4],
        c5 = cuk[5], c6 = cuk[6], c7 = cuk[7], c8 = cuk[8];

    // Q A-fragments: direct b128 loads from pre-scaled bf16 Qb
    const short* qbp = Qb + ((size_t)h * T + t0 + 16 * w + l15) * D + quad * 8;
    short8v aQ0 = *(const short8v*)(qbp);
    short8v aQ1 = *(const short8v*)(qbp + 32);

    // q segment ids (C/D rows 16w + quad*4 + r) + block's k-range
    int segq[4];
    #pragma unroll
    for (int r = 0; r < 4; ++r) {
        int t = t0 + 16 * w + quad * 4 + r;
        segq[r] = (t>=q1)+(t>=q2)+(t>=q3)+(t>=q4)+(t>=q5)+(t>=q6)+(t>=q7);
    }
    int sA = (t0>=q1)+(t0>=q2)+(t0>=q3)+(t0>=q4)+(t0>=q5)+(t0>=q6)+(t0>=q7);
    int tBr = t0 + 63;
    int sB = (tBr>=q1)+(tBr>=q2)+(tBr>=q3)+(tBr>=q4)+(tBr>=q5)+(tBr>=q6)+(tBr>=q7);
    int k_start = c0;
    k_start = (sA>0)?c1:k_start; k_start = (sA>1)?c2:k_start;
    k_start = (sA>2)?c3:k_start; k_start = (sA>3)?c4:k_start;
    k_start = (sA>4)?c5:k_start; k_start = (sA>5)?c6:k_start;
    k_start = (sA>6)?c7:k_start;
    int k_end = c1;
    k_end = (sB>0)?c2:k_end; k_end = (sB>1)?c3:k_end;
    k_end = (sB>2)?c4:k_end; k_end = (sB>3)?c5:k_end;
    k_end = (sB>4)?c6:k_end; k_end = (sB>5)?c7:k_end;
    k_end = (sB>6)?c8:k_end;

    const short* Kbh = Kb + (size_t)h * T * D;
    const short* Vbh = Vb + (size_t)h * D * T;
    const int key0 = tid >> 3;        // 0..31
    const int e8   = (tid & 7) << 3;  // 0..56

    // ones B-frag (bf16 1.0) for the P row-sum MFMA
    short8v ones;
    #pragma unroll
    for (int i = 0; i < 8; ++i) ones[i] = (short)0x3F80;

    floatx4 o[4];
    #pragma unroll
    for (int nt = 0; nt < 4; ++nt) o[nt] = (floatx4){0.f, 0.f, 0.f, 0.f};
    floatx4 lacc = (floatx4){0.f, 0.f, 0.f, 0.f};

    const int kc0 = k_start & ~(BK - 1);

    // initial prefetch (chunk kc0)
    short8v rb0, rb1, rb2, rb3;
    int sgC[4], sgN[4];
    rb0 = *(const short8v*)(Kbh + (size_t)(kc0 + key0)      * D + e8);
    rb1 = *(const short8v*)(Kbh + (size_t)(kc0 + 32 + key0) * D + e8);
    rb2 = *(const short8v*)(Vbh + (size_t)key0        * T + kc0 + e8);
    rb3 = *(const short8v*)(Vbh + (size_t)(32 + key0) * T + kc0 + e8);
    #pragma unroll
    for (int nt = 0; nt < 4; ++nt) sgC[nt] = segArr[kc0 + nt * 16 + l15];

    for (int kc = kc0; kc < k_end; kc += BK) {
        __syncthreads();   // previous chunk's LDS reads complete
        *(short8v*)&sK[key0][e8]       = rb0;
        *(short8v*)&sK[32 + key0][e8]  = rb1;
        *(short8v*)&sVT[key0][e8]      = rb2;
        *(short8v*)&sVT[32 + key0][e8] = rb3;
        __syncthreads();

        // fire next chunk's loads (consumed next iteration)
        int kn = kc + BK;
        if (kn < k_end) {
            rb0 = *(const short8v*)(Kbh + (size_t)(kn + key0)      * D + e8);
            rb1 = *(const short8v*)(Kbh + (size_t)(kn + 32 + key0) * D + e8);
            rb2 = *(const short8v*)(Vbh + (size_t)key0        * T + kn + e8);
            rb3 = *(const short8v*)(Vbh + (size_t)(32 + key0) * T + kn + e8);
            #pragma unroll
            for (int nt = 0; nt < 4; ++nt) sgN[nt] = segArr[kn + nt * 16 + l15];
        }

        // ---- S = Q K^T, fixed-max shift (-8) folded into C-init ----
        floatx4 sacc[4];
        #pragma unroll
        for (int nt = 0; nt < 4; ++nt) {
            sacc[nt] = (floatx4){-8.f, -8.f, -8.f, -8.f};
            short8v b0 = *(const short8v*)&sK[nt * 16 + l15][quad * 8];
            short8v b1 = *(const short8v*)&sK[nt * 16 + l15][32 + quad * 8];
            sacc[nt] = __builtin_amdgcn_mfma_f32_16x16x32_bf16(aQ0, b0, sacc[nt], 0, 0, 0);
            sacc[nt] = __builtin_amdgcn_mfma_f32_16x16x32_bf16(aQ1, b1, sacc[nt], 0, 0, 0);
        }

        // ---- mask + exp, write P (wave-private sP; l via ones-MFMA) ----
        #pragma unroll
        for (int nt = 0; nt < 4; ++nt)
            #pragma unroll
            for (int r = 0; r < 4; ++r) {
                float sc = (sgC[nt] == segq[r]) ? sacc[nt][r] : -1e30f;
                float p  = __expf(sc);           // masked -> exactly 0
                sP[w][quad * 4 + r][nt * 16 + l15] = f2bf(p);
            }
        #pragma unroll
        for (int nt = 0; nt < 4; ++nt) sgC[nt] = sgN[nt];

        // ---- P A-frags (in-wave LDS roundtrip) ----
        short8v aP0 = *(const short8v*)&sP[w][l15][quad * 8];
        short8v aP1 = *(const short8v*)&sP[w][l15][32 + quad * 8];

        // ---- O += P V; l += P . 1 (row sums duplicated across cols) ----
        #pragma unroll
        for (int nt = 0; nt < 4; ++nt) {
            short8v v0 = *(const short8v*)&sVT[nt * 16 + l15][quad * 8];
            short8v v1 = *(const short8v*)&sVT[nt * 16 + l15][32 + quad * 8];
            o[nt] = __builtin_amdgcn_mfma_f32_16x16x32_bf16(aP0, v0, o[nt], 0, 0, 0);
            o[nt] = __builtin_amdgcn_mfma_f32_16x16x32_bf16(aP1, v1, o[nt], 0, 0, 0);
        }
        lacc = __builtin_amdgcn_mfma_f32_16x16x32_bf16(aP0, ones, lacc, 0, 0, 0);
        lacc = __builtin_amdgcn_mfma_f32_16x16x32_bf16(aP1, ones, lacc, 0, 0, 0);
    }

    // ---- epilogue: normalize (lacc already full row sum per lane), store ----
    #pragma unroll
    for (int r = 0; r < 4; ++r) {
        float linv = 1.0f / lacc[r];
        float* op = O + ((size_t)(t0 + 16 * w + quad * 4 + r) * H + h) * D + l15;
        #pragma unroll
        for (int nt = 0; nt < 4; ++nt)
            op[nt * 16] = o[nt][r] * linv;
    }
}

// ---------------- fallback (self-contained, LDS-staged, any T) --------------
__global__ __launch_bounds__(256)
void varlen_attn_fb(const float* __restrict__ Q, const float* __restrict__ K,
                    const float* __restrict__ V, const int* __restrict__ cuq,
                    const int* __restrict__ cuk, float* __restrict__ O, int T)
{
    __shared__ short sKf[64][LDK];
    __shared__ short sVf[D][72];
    __shared__ short sPf[4][16][72];
    __shared__ int   sSegK[64];
    __shared__ int   sCuQ[NSEG + 1], sCuK[NSEG + 1];

    const int tid  = threadIdx.x;
    const int lane = tid & 63;
    const int w    = tid >> 6;
    const int quad = lane >> 4;
    const int l15  = lane & 15;
    const int h    = blockIdx.x % H;
    const int t0   = (blockIdx.x / H) * 64;

    if (tid <= NSEG) { sCuQ[tid] = cuq[tid]; sCuK[tid] = cuk[tid]; }
    __syncthreads();

    int qrow = t0 + 16 * w + l15; if (qrow >= T) qrow = T - 1;
    const float* qp = Q + ((size_t)qrow * H + h) * D + quad * 8;
    short8v aQ0, aQ1;
    {
        float4 a = *(const float4*)(qp);
        float4 b = *(const float4*)(qp + 4);
        float4 c = *(const float4*)(qp + 32);
        float4 e = *(const float4*)(qp + 36);
        aQ0[0]=f2bf(a.x*0.125f); aQ0[1]=f2bf(a.y*0.125f);
        aQ0[2]=f2bf(a.z*0.125f); aQ0[3]=f2bf(a.w*0.125f);
        aQ0[4]=f2bf(b.x*0.125f); aQ0[5]=f2bf(b.y*0.125f);
        aQ0[6]=f2bf(b.z*0.125f); aQ0[7]=f2bf(b.w*0.125f);
        aQ1[0]=f2bf(c.x*0.125f); aQ1[1]=f2bf(c.y*0.125f);
        aQ1[2]=f2bf(c.z*0.125f); aQ1[3]=f2bf(c.w*0.125f);
        aQ1[4]=f2bf(e.x*0.125f); aQ1[5]=f2bf(e.y*0.125f);
        aQ1[6]=f2bf(e.z*0.125f); aQ1[7]=f2bf(e.w*0.125f);
    }

    int segq[4];
    #pragma unroll
    for (int r = 0; r < 4; ++r) {
        int t = t0 + 16 * w + quad * 4 + r; if (t >= T) t = T - 1;
        int s = 0;
        while (s < NSEG - 1 && t >= sCuQ[s + 1]) ++s;
        segq[r] = s;
    }
    int k_start, k_end;
    {
        int tA = t0; if (tA >= T) tA = T - 1;
        int tB = t0 + 63; if (tB >= T) tB = T - 1;
        int sA2 = 0; while (sA2 < NSEG - 1 && tA >= sCuQ[sA2 + 1]) ++sA2;
        int sB2 = 0; while (sB2 < NSEG - 1 && tB >= sCuQ[sB2 + 1]) ++sB2;
        k_start = sCuK[sA2];
        k_end   = sCuK[sB2 + 1];
    }

    floatx4 o[4];
    #pragma unroll
    for (int nt = 0; nt < 4; ++nt) o[nt] = (floatx4){0.f, 0.f, 0.f, 0.f};
    float l_r[4] = {0.f, 0.f, 0.f, 0.f};

    for (int kc = k_start; kc < k_end; kc += 64) {
        __syncthreads();
        for (int i = tid; i < 64 * D / 4; i += 256) {
            int k = i >> 4;
            int c = (i & 15) << 2;
            int kt = kc + k;
            float4 kv = {0,0,0,0}, vv = {0,0,0,0};
            if (kt < k_end) {
                kv = *(const float4*)&K[((size_t)kt * H + h) * D + c];
                vv = *(const float4*)&V[((size_t)kt * H + h) * D + c];
            }
            short4v ks;
            ks.x=f2bf(kv.x); ks.y=f2bf(kv.y); ks.z=f2bf(kv.z); ks.w=f2bf(kv.w);
            *(short4v*)&sKf[k][c] = ks;
            sVf[c+0][k]=f2bf(vv.x); sVf[c+1][k]=f2bf(vv.y);
            sVf[c+2][k]=f2bf(vv.z); sVf[c+3][k]=f2bf(vv.w);
        }
        if (tid < 64) {
            int kt = kc + tid;
            int s = -1;
            if (kt < k_end) { s = 0; while (s < NSEG - 1 && kt >= sCuK[s + 1]) ++s; }
            sSegK[tid] = s;
        }
        __syncthreads();

        floatx4 sacc[4];
        #pragma unroll
        for (int nt = 0; nt < 4; ++nt) {
            sacc[nt] = (floatx4){-8.f, -8.f, -8.f, -8.f};
            short8v b0 = *(const short8v*)&sKf[nt * 16 + l15][quad * 8];
            short8v b1 = *(const short8v*)&sKf[nt * 16 + l15][32 + quad * 8];
            sacc[nt] = __builtin_amdgcn_mfma_f32_16x16x32_bf16(aQ0, b0, sacc[nt], 0, 0, 0);
            sacc[nt] = __builtin_amdgcn_mfma_f32_16x16x32_bf16(aQ1, b1, sacc[nt], 0, 0, 0);
        }
        #pragma unroll
        for (int nt = 0; nt < 4; ++nt) {
            int segk = sSegK[nt * 16 + l15];
            #pragma unroll
            for (int r = 0; r < 4; ++r) {
                float sc = (segk == segq[r]) ? sacc[nt][r] : -1e30f;
                float p  = __expf(sc);
                l_r[r] += p;
                sPf[w][quad * 4 + r][nt * 16 + l15] = f2bf(p);
            }
        }
        short8v aP0 = *(const short8v*)&sPf[w][l15][quad * 8];
        short8v aP1 = *(const short8v*)&sPf[w][l15][32 + quad * 8];
        #pragma unroll
        for (int nt = 0; nt < 4; ++nt) {
            short8v b0 = *(const short8v*)&sVf[nt * 16 + l15][quad * 8];
            short8v b1 = *(const short8v*)&sVf[nt * 16 + l15][32 + quad * 8];
            o[nt] = __builtin_amdgcn_mfma_f32_16x16x32_bf16(aP0, b0, o[nt], 0, 0, 0);
            o[nt] = __builtin_amdgcn_mfma_f32_16x16x32_bf16(aP1, b1, o[nt], 0, 0, 0);
        }
    }

    #pragma unroll
    for (int off = 1; off < 16; off <<= 1)
        #pragma unroll
        for (int r = 0; r < 4; ++r)
            l_r[r] += __shfl_xor(l_r[r], off);

    #pragma unroll
    for (int r = 0; r < 4; ++r) {
        int trow = t0 + 16 * w + quad * 4 + r;
        if (trow < T) {
            float linv = 1.0f / l_r[r];
            float* op = O + ((size_t)trow * H + h) * D + l15;
            #pragma unroll
            for (int nt = 0; nt < 4; ++nt)
                op[nt * 16] = o[nt][r] * linv;
        }
    }
}

extern "C" void kernel_launch(void* const* d_in, const int* in_sizes, int n_in,
                              void* d_out, int out_size, void* d_ws, size_t ws_size,
                              hipStream_t stream) {
    const float* Q = (const float*)d_in[0];
    const float* K = (const float*)d_in[1];
    const float* V = (const float*)d_in[2];
    const int* cuq = (const int*)d_in[3];
    const int* cuk = (const int*)d_in[4];
    float* O = (float*)d_out;

    int T = in_sizes[0] / (H * D);
    size_t need = (size_t)3 * H * T * D * sizeof(short) + (size_t)T * sizeof(int);

    if (ws_size >= need && (T & 63) == 0) {
        short* Qb = (short*)d_ws;
        short* Kb = Qb + (size_t)H * T * D;
        short* Vb = Kb + (size_t)H * T * D;
        int*   segArr = (int*)(Vb + (size_t)H * T * D);

        hipLaunchKernelGGL(prepass_qkv, dim3(H * (T >> 6)), dim3(256), 0, stream,
                           Q, K, V, cuk, Qb, Kb, Vb, segArr, T);
        hipLaunchKernelGGL(varlen_attn9, dim3((T / 64) * H), dim3(256), 0, stream,
                           Qb, Kb, Vb, segArr, cuq, cuk, O, T);
    } else {
        int nQT = (T + 63) / 64;
        hipLaunchKernelGGL(varlen_attn_fb, dim3(nQT * H), dim3(256), 0, stream,
                           Q, K, V, cuq, cuk, O, T);
    }
}